// Round 15
// baseline (122.063 us; speedup 1.0000x reference)
//
#include <hip/hip_runtime.h>
#include <hip/hip_bf16.h>
#include <math.h>

// Decoder: h = relu(cat @ W_h + b_h); t = selu(h @ W1 + b1);
// x = sigmoid(t @ W2 + b2); loss = sum_w(softplus(z) - z*img)   [== -(BCE log-lik)]
// R = S*B = 4096 rows; Hn=512, bott=160, P=12288 = 192 groups * 64 (w).

#define SELU_SCALE 1.0507009873554804934193349852946f
#define SELU_ALPHA 1.6732632423543772848170429916717f

typedef __attribute__((ext_vector_type(8))) short bf16x8;   // 8 bf16 (4 VGPRs)
typedef __attribute__((ext_vector_type(4))) float f32x4;    // MFMA accumulator

static __device__ __forceinline__ short f2bf(float x) {
    __hip_bfloat16 h = __float2bfloat16(x);
    short s;
    __builtin_memcpy(&s, &h, 2);
    return s;
}

// ---------------- K0: pack W2 into MFMA-fragment-native order --------------
// w2f chunk = (col16*5 + kk): 64 lanes x 8 bf16 (1 KB contiguous).
__global__ __launch_bounds__(256) void w2_pack_kernel(
    const float* __restrict__ W2,       // [160,12288]
    __hip_bfloat16* __restrict__ w2f)   // [768*5 chunks][512 shorts]
{
    __shared__ float tile[32][64];      // [k within 32][col within 64]
    const int colBase = blockIdx.x * 64;   // 192
    const int kkBase  = blockIdx.y * 32;   // 5
    const int tid = threadIdx.x;

    for (int i = tid; i < 32 * 64; i += 256)
        tile[i >> 6][i & 63] = W2[(size_t)(kkBase + (i >> 6)) * 12288 + colBase + (i & 63)];
    __syncthreads();

    const int c16 = tid >> 6;        // 0..3 (col16 within this block)
    const int lane = tid & 63;
    const int lr = lane & 15, lh = lane >> 4;

    bf16x8 v;
#pragma unroll
    for (int j = 0; j < 8; ++j)
        v[j] = f2bf(tile[lh * 8 + j][c16 * 16 + lr]);

    const size_t chunk = (size_t)(blockIdx.x * 4 + c16) * 5 + blockIdx.y;
    *(bf16x8*)((short*)w2f + chunk * 512 + lane * 8) = v;
}

// ---------------- K1': FUSED h -> t -> tf (h,t never touch HBM) ------------
// Block = 16 rows (one r16 chunk group), 512 threads, grid 256. (R14-verified)
__global__ __launch_bounds__(512) void dec_fused_kernel(
    const float* __restrict__ digits,   // [R,10]
    const float* __restrict__ styles,   // [R,50]
    const float* __restrict__ Wh,       // [60,512]
    const float* __restrict__ bh,       // [512]
    const float* __restrict__ W1,       // [512,160]
    const float* __restrict__ b1,       // [160]
    __hip_bfloat16* __restrict__ tf)    // [1280 chunks][512 shorts]
{
    __shared__ float cat_s[16][60];     // 3.75 KB
    __shared__ float h_s[16 * 512];     // 32 KB
    __shared__ float t_s[16][161];      // 10.1 KB (pad: conflict-free pack)

    const int tid = threadIdx.x;
    const int rowBase = blockIdx.x * 16;

    // ---- A: stage concat rows ----
    for (int i = tid; i < 16 * 60; i += 512) {
        const int r = i / 60, k = i % 60;
        const int row = rowBase + r;
        cat_s[r][k] = (k < 10) ? digits[row * 10 + k]
                               : styles[row * 50 + (k - 10)];
    }
    __syncthreads();

    // ---- B: h = relu(cat @ Wh + bh); thread = one column, 16 rows ----
    {
        float acc[16];
        const float bias = bh[tid];
#pragma unroll
        for (int r = 0; r < 16; ++r) acc[r] = bias;
        for (int k = 0; k < 60; ++k) {
            const float w = Wh[k * 512 + tid];
#pragma unroll
            for (int r = 0; r < 16; ++r) acc[r] = fmaf(cat_s[r][k], w, acc[r]);
        }
#pragma unroll
        for (int r = 0; r < 16; ++r)
            h_s[r * 512 + tid] = fmaxf(acc[r], 0.0f);
    }
    __syncthreads();

    // ---- C: t = selu(h @ W1 + b1); 320 threads = 160 cols x 2 row-halves --
    if (tid < 320) {
        const int rh = (tid >= 160) ? 1 : 0;
        const int col = tid - rh * 160;
        const int r0 = rh * 8;
        float acc[8];
        const float bias = b1[col];
#pragma unroll
        for (int r = 0; r < 8; ++r) acc[r] = bias;

        for (int k = 0; k < 512; k += 4) {
            const float w0 = W1[(size_t)(k + 0) * 160 + col];
            const float w1 = W1[(size_t)(k + 1) * 160 + col];
            const float w2 = W1[(size_t)(k + 2) * 160 + col];
            const float w3 = W1[(size_t)(k + 3) * 160 + col];
#pragma unroll
            for (int r = 0; r < 8; ++r) {
                const float4 hv = *(const float4*)&h_s[(r0 + r) * 512 + k];
                float a = acc[r];
                a = fmaf(hv.x, w0, a);
                a = fmaf(hv.y, w1, a);
                a = fmaf(hv.z, w2, a);
                a = fmaf(hv.w, w3, a);
                acc[r] = a;
            }
        }
#pragma unroll
        for (int r = 0; r < 8; ++r) {
            const float z = acc[r];
            const float s = (z > 0.0f) ? (SELU_SCALE * z)
                                       : (SELU_SCALE * SELU_ALPHA * expm1f(z));
            t_s[r0 + r][col] = s;
        }
    }
    __syncthreads();

    // ---- D: pack 5 chunks (kk=0..4), 64 lanes each ----
    if (tid < 320) {
        const int kk = tid >> 6;        // 0..4
        const int l = tid & 63;
        const int lr = l & 15, lh = l >> 4;
        bf16x8 v;
#pragma unroll
        for (int j = 0; j < 8; ++j)
            v[j] = f2bf(t_s[lr][kk * 32 + lh * 8 + j]);
        *(bf16x8*)((short*)tf + ((size_t)blockIdx.x * 5 + kk) * 512 + l * 8) = v;
    }
}

// ---------------- K3: sustained-stream MFMA GEMM + fused BCE loss ----------
// grid (48, 64) col-fast; block 256 = 4 waves; wave = 16 rows x 4 sequential
// 64-col tiles (cols blockIdx.x*256 + it*64). Per-wave 2 alternating 4 KB
// image slabs (32 KB/block -> 5 blocks/CU, 20 waves). Sustained pipeline:
// tile it+1's 4 DMAs are issued every iteration; the epilogue fence is a
// COUNTED s_waitcnt vmcnt(4) (leaves next-tile DMAs in flight; never drains
// to 0 mid-loop -- the T4 pattern R13 got wrong). bc loads are placed BEFORE
// the DMAs so their compiler wait is vmcnt(4), not a drain. t-fragments are
// register-cached (rows fixed per wave). VGPR ~85 <= 102 cap.
__global__ __launch_bounds__(256, 5) void out_loss_mfma_kernel(
    const __hip_bfloat16* __restrict__ tf,   // fragment-packed t
    const __hip_bfloat16* __restrict__ w2f,  // fragment-packed W2
    const float* __restrict__ b2,            // [12288]
    const float* __restrict__ images,        // [4096,12288]
    float* __restrict__ out)                 // [4096,192]
{
    __shared__ float ims[4][2][1024];        // 32 KB: per-wave 2 x (16r x 64c)

    const int tid = threadIdx.x;
    const int lane = tid & 63;
    const int wv = tid >> 6;
    const int rowBase = blockIdx.y * 64 + wv * 16;   // wave's 16 t-rows
    const int colBase0 = blockIdx.x * 256;           // 4 w-groups
    const int lr = lane & 15;
    const int lh = lane >> 4;

    const short* wfb = (const short*)w2f;
    const short* tfb = (const short*)tf;
    const char* imb = (const char*)images;
    const int r16 = rowBase >> 4;

    // DMA source helper indices (4 instrs x 4 rows; pre-swizzled chunks)
    const int rsub = lane >> 4;          // row within instruction (0..3)
    const int m16 = lane & 15;           // 16B chunk within 256B row

    // ---- bT: t fragments for these 16 rows, register-cached (20 VGPR) ----
    bf16x8 bT[5];
#pragma unroll
    for (int kk = 0; kk < 5; ++kk)
        bT[kk] = *(const bf16x8*)(tfb + ((size_t)r16 * 5 + kk) * 512 + lane * 8);

    // ---- prologue: DMA tile 0 into slab 0 ----
#pragma unroll
    for (int w = 0; w < 4; ++w) {
        const int r = w * 4 + rsub;
        const size_t gb = (size_t)(rowBase + r) * 49152 + (size_t)colBase0 * 4
                        + (size_t)((16 * m16) ^ ((r & 15) << 4));
        __builtin_amdgcn_global_load_lds((const uint32_t*)(imb + gb),
            (uint32_t*)&ims[wv][0][w * 256], 16, 0, 0);
    }

#pragma unroll
    for (int it = 0; it < 4; ++it) {
        const int colB = colBase0 + it * 64;
        const int c16b = colB >> 4;

        // ---- GEMM tile it: aW from L2 (packed 1-segment), bT cached ----
        f32x4 acc[4] = {};
#pragma unroll
        for (int kk = 0; kk < 5; ++kk) {
            bf16x8 aW[4];
#pragma unroll
            for (int c = 0; c < 4; ++c)
                aW[c] = *(const bf16x8*)(wfb
                    + ((size_t)(c16b + c) * 5 + kk) * 512 + lane * 8);
#pragma unroll
            for (int c = 0; c < 4; ++c)
                acc[c] = __builtin_amdgcn_mfma_f32_16x16x32_bf16(
                    aW[c], bT[kk], acc[c], 0, 0, 0);
        }

        // bias quads BEFORE the next DMAs (so their wait = vmcnt(4), no drain)
        float4 bc[4];
#pragma unroll
        for (int c = 0; c < 4; ++c)
            bc[c] = *(const float4*)(b2 + colB + c * 16 + lh * 4);

        // ---- issue tile it+1's DMAs into the other slab ----
        if (it < 3) {
            const int colN = colBase0 + (it + 1) * 64;
#pragma unroll
            for (int w = 0; w < 4; ++w) {
                const int r = w * 4 + rsub;
                const size_t gb = (size_t)(rowBase + r) * 49152
                                + (size_t)colN * 4
                                + (size_t)((16 * m16) ^ ((r & 15) << 4));
                __builtin_amdgcn_global_load_lds((const uint32_t*)(imb + gb),
                    (uint32_t*)&ims[wv][(it + 1) & 1][w * 256], 16, 0, 0);
            }
            // counted fence: at most 4 outstanding (= the next-tile DMAs).
            // Guarantees current slab + bc landed; keeps the pipe primed.
            asm volatile("s_waitcnt vmcnt(4)" ::: "memory");
        } else {
            asm volatile("s_waitcnt vmcnt(0)" ::: "memory");
        }

        // ---- epilogue: softplus(z) - z*img over 16 rows x 64 cols ----
        const float* slab = ims[wv][it & 1];
        float mx = 0.f;   // Σ max(z,0)
        float pr = 1.f;   // Π (1+e^{-|z|})  (16 terms, fp32-safe)
        float zi = 0.f;   // Σ z*im
#pragma unroll
        for (int c = 0; c < 4; ++c) {
            const int fidx = lr * 64 + ((lh * 4 + c * 16) ^ (lr << 2));
            const float4 im4 = *(const float4*)&slab[fidx];   // ds_read_b128
            const float imv[4] = {im4.x, im4.y, im4.z, im4.w};
            const float bcv[4] = {bc[c].x, bc[c].y, bc[c].z, bc[c].w};
#pragma unroll
            for (int j = 0; j < 4; ++j) {
                const float z = acc[c][j] + bcv[j];
                mx += fmaxf(z, 0.0f);
                pr *= 1.0f + __expf(-fabsf(z));   // native v_exp_f32
                zi = fmaf(z, imv[j], zi);
            }
        }
        float part = mx + __logf(pr) - zi;        // native v_log_f32

        // reduce over the 4 lh groups (each holds 16 of the 64 w-cols)
        part += __shfl_xor(part, 16);
        part += __shfl_xor(part, 32);

        if (lane < 16)
            out[(size_t)(rowBase + lane) * 192 + blockIdx.x * 4 + it] = part;
    }
}

extern "C" void kernel_launch(void* const* d_in, const int* in_sizes, int n_in,
                              void* d_out, int out_size, void* d_ws, size_t ws_size,
                              hipStream_t stream) {
    const float* digits = (const float*)d_in[0];  // [8,512,10]
    const float* styles = (const float*)d_in[1];  // [8,512,50]
    const float* images = (const float*)d_in[2];  // [8,512,3,64,64]
    const float* Wh     = (const float*)d_in[3];  // [60,512]
    const float* bh     = (const float*)d_in[4];  // [512]
    const float* W1     = (const float*)d_in[5];  // [512,160]
    const float* b1     = (const float*)d_in[6];  // [160]
    const float* W2     = (const float*)d_in[7];  // [160,12288]
    const float* b2     = (const float*)d_in[8];  // [12288]
    float* out = (float*)d_out;                   // [4096,192]

    // workspace (~5.3 MB): w2f bf16 [3840*512] | tf bf16 [1280*512]
    __hip_bfloat16* w2f = (__hip_bfloat16*)d_ws;
    __hip_bfloat16* tf  = w2f + (size_t)12288 * 160;

    dim3 gridP(192, 5);
    w2_pack_kernel<<<gridP, 256, 0, stream>>>(W2, w2f);

    dec_fused_kernel<<<256, 512, 0, stream>>>(digits, styles, Wh, bh, W1, b1, tf);

    dim3 grid3(48, 64);
    out_loss_mfma_kernel<<<grid3, 256, 0, stream>>>(tf, w2f, b2, images, out);
}

// Round 16
// 86.407 us; speedup vs baseline: 1.4127x; 1.4127x over previous
//
#include <hip/hip_runtime.h>
#include <hip/hip_bf16.h>
#include <math.h>

// Decoder: h = relu(cat @ W_h + b_h); t = selu(h @ W1 + b1);
// x = sigmoid(t @ W2 + b2); loss = sum_w(softplus(z) - z*img)   [== -(BCE log-lik)]
// R = S*B = 4096 rows; Hn=512, bott=160, P=12288 = 192 groups * 64 (w).

#define SELU_SCALE 1.0507009873554804934193349852946f
#define SELU_ALPHA 1.6732632423543772848170429916717f

typedef __attribute__((ext_vector_type(8))) short bf16x8;   // 8 bf16 (4 VGPRs)
typedef __attribute__((ext_vector_type(4))) float f32x4;    // MFMA accumulator

static __device__ __forceinline__ short f2bf(float x) {
    __hip_bfloat16 h = __float2bfloat16(x);
    short s;
    __builtin_memcpy(&s, &h, 2);
    return s;
}

// ---------------- K0: pack W2 into MFMA-fragment-native order --------------
// w2f chunk = (col16*5 + kk): 64 lanes x 8 bf16 (1 KB contiguous).
__global__ __launch_bounds__(256) void w2_pack_kernel(
    const float* __restrict__ W2,       // [160,12288]
    __hip_bfloat16* __restrict__ w2f)   // [768*5 chunks][512 shorts]
{
    __shared__ float tile[32][64];      // [k within 32][col within 64]
    const int colBase = blockIdx.x * 64;   // 192
    const int kkBase  = blockIdx.y * 32;   // 5
    const int tid = threadIdx.x;

    for (int i = tid; i < 32 * 64; i += 256)
        tile[i >> 6][i & 63] = W2[(size_t)(kkBase + (i >> 6)) * 12288 + colBase + (i & 63)];
    __syncthreads();

    const int c16 = tid >> 6;        // 0..3 (col16 within this block)
    const int lane = tid & 63;
    const int lr = lane & 15, lh = lane >> 4;

    bf16x8 v;
#pragma unroll
    for (int j = 0; j < 8; ++j)
        v[j] = f2bf(tile[lh * 8 + j][c16 * 16 + lr]);

    const size_t chunk = (size_t)(blockIdx.x * 4 + c16) * 5 + blockIdx.y;
    *(bf16x8*)((short*)w2f + chunk * 512 + lane * 8) = v;
}

// ---------------- K1': FUSED h -> t -> tf (h,t never touch HBM) ------------
// Block = 16 rows (one r16 chunk group), 512 threads, grid 256. (R14-verified)
__global__ __launch_bounds__(512) void dec_fused_kernel(
    const float* __restrict__ digits,   // [R,10]
    const float* __restrict__ styles,   // [R,50]
    const float* __restrict__ Wh,       // [60,512]
    const float* __restrict__ bh,       // [512]
    const float* __restrict__ W1,       // [512,160]
    const float* __restrict__ b1,       // [160]
    __hip_bfloat16* __restrict__ tf)    // [1280 chunks][512 shorts]
{
    __shared__ float cat_s[16][60];     // 3.75 KB
    __shared__ float h_s[16 * 512];     // 32 KB
    __shared__ float t_s[16][161];      // 10.1 KB (pad: conflict-free pack)

    const int tid = threadIdx.x;
    const int rowBase = blockIdx.x * 16;

    // ---- A: stage concat rows ----
    for (int i = tid; i < 16 * 60; i += 512) {
        const int r = i / 60, k = i % 60;
        const int row = rowBase + r;
        cat_s[r][k] = (k < 10) ? digits[row * 10 + k]
                               : styles[row * 50 + (k - 10)];
    }
    __syncthreads();

    // ---- B: h = relu(cat @ Wh + bh); thread = one column, 16 rows ----
    {
        float acc[16];
        const float bias = bh[tid];
#pragma unroll
        for (int r = 0; r < 16; ++r) acc[r] = bias;
        for (int k = 0; k < 60; ++k) {
            const float w = Wh[k * 512 + tid];
#pragma unroll
            for (int r = 0; r < 16; ++r) acc[r] = fmaf(cat_s[r][k], w, acc[r]);
        }
#pragma unroll
        for (int r = 0; r < 16; ++r)
            h_s[r * 512 + tid] = fmaxf(acc[r], 0.0f);
    }
    __syncthreads();

    // ---- C: t = selu(h @ W1 + b1); 320 threads = 160 cols x 2 row-halves --
    if (tid < 320) {
        const int rh = (tid >= 160) ? 1 : 0;
        const int col = tid - rh * 160;
        const int r0 = rh * 8;
        float acc[8];
        const float bias = b1[col];
#pragma unroll
        for (int r = 0; r < 8; ++r) acc[r] = bias;

        for (int k = 0; k < 512; k += 4) {
            const float w0 = W1[(size_t)(k + 0) * 160 + col];
            const float w1 = W1[(size_t)(k + 1) * 160 + col];
            const float w2 = W1[(size_t)(k + 2) * 160 + col];
            const float w3 = W1[(size_t)(k + 3) * 160 + col];
#pragma unroll
            for (int r = 0; r < 8; ++r) {
                const float4 hv = *(const float4*)&h_s[(r0 + r) * 512 + k];
                float a = acc[r];
                a = fmaf(hv.x, w0, a);
                a = fmaf(hv.y, w1, a);
                a = fmaf(hv.z, w2, a);
                a = fmaf(hv.w, w3, a);
                acc[r] = a;
            }
        }
#pragma unroll
        for (int r = 0; r < 8; ++r) {
            const float z = acc[r];
            const float s = (z > 0.0f) ? (SELU_SCALE * z)
                                       : (SELU_SCALE * SELU_ALPHA * expm1f(z));
            t_s[r0 + r][col] = s;
        }
    }
    __syncthreads();

    // ---- D: pack 5 chunks (kk=0..4), 64 lanes each ----
    if (tid < 320) {
        const int kk = tid >> 6;        // 0..4
        const int l = tid & 63;
        const int lr = l & 15, lh = l >> 4;
        bf16x8 v;
#pragma unroll
        for (int j = 0; j < 8; ++j)
            v[j] = f2bf(t_s[lr][kk * 32 + lh * 8 + j]);
        *(bf16x8*)((short*)tf + ((size_t)blockIdx.x * 5 + kk) * 512 + l * 8) = v;
    }
}

// ---------------- K3: LDS-operand MFMA GEMM + fused sigmoid-BCE loss -------
// grid (192, 32) col-fast; block 256 = 4 waves stacked on rows; tile 128x64.
// Root cause of R10-R15's ~2 TB/s ceiling: GEMM operand loads from L2
// serialized per-wave (exposed L2 latency). Fix (R9-verified staging +
// R10-verified statelessness):
//  - w2s: block's 20 w2f chunks DMA'd into LDS ONCE, SHARED by all 4 waves
//    (5 DMAs/wave, per-lane source + linear dest).
//  - images: per-wave private LDS slab via DMA (R6 swizzle).
//  - bT (40 VGPR) + bc (16 VGPR): register loads issued pre-barrier.
//  - ONE __syncthreads; after it everything is LDS/register-local: GEMM
//    reads aW via ds_read_b128 (lane-contiguous, m97 pattern), zero global.
// 52 KB LDS -> 3 blocks/CU; inter-block stagger hides the pre-barrier wait.
__global__ __launch_bounds__(256, 3) void out_loss_mfma_kernel(
    const __hip_bfloat16* __restrict__ tf,   // fragment-packed t
    const __hip_bfloat16* __restrict__ w2f,  // fragment-packed W2
    const float* __restrict__ b2,            // [12288]
    const float* __restrict__ images,        // [4096,12288]
    float* __restrict__ out)                 // [4096,192]
{
    __shared__ short w2s[20 * 512];          // 20 KB: block's w2 chunks
    __shared__ float ims[4][2048];           // 32 KB: per-wave 32x64 images

    const int tid = threadIdx.x;
    const int lane = tid & 63;
    const int wv = tid >> 6;
    const int rowBase = blockIdx.y * 128 + wv * 32;
    const int colBase = blockIdx.x * 64;
    const int lr = lane & 15;
    const int lh = lane >> 4;

    const short* wfb = (const short*)w2f;
    const short* tfb = (const short*)tf;
    const char* imb = (const char*)images;

    // ---- stage w2s: 20 chunks, 5 per wave, shared across block ----
    {
        const size_t chunkBase = (size_t)blockIdx.x * 20;
#pragma unroll
        for (int tch = 0; tch < 5; ++tch) {
            const int cw = wv + tch * 4;
            __builtin_amdgcn_global_load_lds(
                (const uint32_t*)(wfb + (chunkBase + cw) * 512 + lane * 8),
                (uint32_t*)&w2s[cw * 512], 16, 0, 0);
        }
    }
    // ---- stage images: per-wave private 32x64 (8 DMAs, pre-swizzled) ----
    {
        const int rsub = lane >> 4;
        const int m = lane & 15;
#pragma unroll
        for (int w = 0; w < 8; ++w) {
            const int r = w * 4 + rsub;
            const size_t gb = (size_t)(rowBase + r) * 49152 + (size_t)colBase * 4
                            + (size_t)((16 * m) ^ ((r & 15) << 4));
            __builtin_amdgcn_global_load_lds((const uint32_t*)(imb + gb),
                (uint32_t*)&ims[wv][w * 256], 16, 0, 0);
        }
    }

    // ---- bT + bc to registers, issued pre-barrier (drained by it) ----
    const int r16base = rowBase >> 4;
    bf16x8 bT[5][2];
#pragma unroll
    for (int kk = 0; kk < 5; ++kk)
#pragma unroll
        for (int r = 0; r < 2; ++r)
            bT[kk][r] = *(const bf16x8*)(tfb
                + ((size_t)(r16base + r) * 5 + kk) * 512 + lane * 8);
    float4 bc[4];
#pragma unroll
    for (int c = 0; c < 4; ++c)
        bc[c] = *(const float4*)(b2 + colBase + c * 16 + lh * 4);

    __syncthreads();   // single barrier: w2s, ims, bT, bc all resident

    // ---- GEMM: aW from LDS, bT from regs (zero global after barrier) ----
    f32x4 acc[4][2] = {};   // [cw][rw]
#pragma unroll
    for (int kk = 0; kk < 5; ++kk) {
        bf16x8 aW[4];
#pragma unroll
        for (int c = 0; c < 4; ++c)
            aW[c] = *(const bf16x8*)&w2s[(c * 5 + kk) * 512 + lane * 8];
#pragma unroll
        for (int c = 0; c < 4; ++c)
#pragma unroll
            for (int r = 0; r < 2; ++r)
                acc[c][r] = __builtin_amdgcn_mfma_f32_16x16x32_bf16(
                    aW[c], bT[kk][r], acc[c][r], 0, 0, 0);
    }

    // ---- epilogue: softplus(z) - z*img, reduce over 64 cols ----
    const float* myq = ims[wv];
#pragma unroll
    for (int rw = 0; rw < 2; ++rw) {
        float mx = 0.f;   // Σ max(z,0)
        float pr = 1.f;   // Π (1+e^{-|z|})  (16 terms, fp32-safe)
        float zi = 0.f;   // Σ z*im
#pragma unroll
        for (int c = 0; c < 4; ++c) {
            const int fidx = (rw * 16 + lr) * 64 + ((lh * 4 + c * 16) ^ (lr << 2));
            const float4 im4 = *(const float4*)&myq[fidx];   // ds_read_b128
            const float imv[4] = {im4.x, im4.y, im4.z, im4.w};
            const float bcv[4] = {bc[c].x, bc[c].y, bc[c].z, bc[c].w};
#pragma unroll
            for (int j = 0; j < 4; ++j) {
                const float z = acc[c][rw][j] + bcv[j];
                mx += fmaxf(z, 0.0f);
                pr *= 1.0f + __expf(-fabsf(z));   // native v_exp_f32
                zi = fmaf(z, imv[j], zi);
            }
        }
        float part = mx + __logf(pr) - zi;        // native v_log_f32

        // reduce over the 4 lh groups (each holds 16 of the 64 w-cols)
        part += __shfl_xor(part, 16);
        part += __shfl_xor(part, 32);

        if (lane < 16)
            out[(size_t)(rowBase + rw * 16 + lane) * 192 + blockIdx.x] = part;
    }
}

extern "C" void kernel_launch(void* const* d_in, const int* in_sizes, int n_in,
                              void* d_out, int out_size, void* d_ws, size_t ws_size,
                              hipStream_t stream) {
    const float* digits = (const float*)d_in[0];  // [8,512,10]
    const float* styles = (const float*)d_in[1];  // [8,512,50]
    const float* images = (const float*)d_in[2];  // [8,512,3,64,64]
    const float* Wh     = (const float*)d_in[3];  // [60,512]
    const float* bh     = (const float*)d_in[4];  // [512]
    const float* W1     = (const float*)d_in[5];  // [512,160]
    const float* b1     = (const float*)d_in[6];  // [160]
    const float* W2     = (const float*)d_in[7];  // [160,12288]
    const float* b2     = (const float*)d_in[8];  // [12288]
    float* out = (float*)d_out;                   // [4096,192]

    // workspace (~5.3 MB): w2f bf16 [3840*512] | tf bf16 [1280*512]
    __hip_bfloat16* w2f = (__hip_bfloat16*)d_ws;
    __hip_bfloat16* tf  = w2f + (size_t)12288 * 160;

    dim3 gridP(192, 5);
    w2_pack_kernel<<<gridP, 256, 0, stream>>>(W2, w2f);

    dec_fused_kernel<<<256, 512, 0, stream>>>(digits, styles, Wh, bh, W1, b1, tf);

    dim3 grid3(192, 32);
    out_loss_mfma_kernel<<<grid3, 256, 0, stream>>>(tf, w2f, b2, images, out);
}

// Round 17
// 85.656 us; speedup vs baseline: 1.4250x; 1.0088x over previous
//
#include <hip/hip_runtime.h>
#include <hip/hip_bf16.h>
#include <math.h>

// Decoder: h = relu(cat @ W_h + b_h); t = selu(h @ W1 + b1);
// x = sigmoid(t @ W2 + b2); loss = sum_w(softplus(z) - z*img)   [== -(BCE log-lik)]
// R = S*B = 4096 rows; Hn=512, bott=160, P=12288 = 192 groups * 64 (w).

#define SELU_SCALE 1.0507009873554804934193349852946f
#define SELU_ALPHA 1.6732632423543772848170429916717f

typedef __attribute__((ext_vector_type(8))) short bf16x8;   // 8 bf16 (4 VGPRs)
typedef __attribute__((ext_vector_type(4))) float f32x4;    // MFMA accumulator

static __device__ __forceinline__ short f2bf(float x) {
    __hip_bfloat16 h = __float2bfloat16(x);
    short s;
    __builtin_memcpy(&s, &h, 2);
    return s;
}

// ---------------- K0: pack W2 into MFMA-fragment-native order --------------
// w2f chunk = (col16*5 + kk): 64 lanes x 8 bf16 (1 KB contiguous).
__global__ __launch_bounds__(256) void w2_pack_kernel(
    const float* __restrict__ W2,       // [160,12288]
    __hip_bfloat16* __restrict__ w2f)   // [768*5 chunks][512 shorts]
{
    __shared__ float tile[32][64];      // [k within 32][col within 64]
    const int colBase = blockIdx.x * 64;   // 192
    const int kkBase  = blockIdx.y * 32;   // 5
    const int tid = threadIdx.x;

    for (int i = tid; i < 32 * 64; i += 256)
        tile[i >> 6][i & 63] = W2[(size_t)(kkBase + (i >> 6)) * 12288 + colBase + (i & 63)];
    __syncthreads();

    const int c16 = tid >> 6;        // 0..3 (col16 within this block)
    const int lane = tid & 63;
    const int lr = lane & 15, lh = lane >> 4;

    bf16x8 v;
#pragma unroll
    for (int j = 0; j < 8; ++j)
        v[j] = f2bf(tile[lh * 8 + j][c16 * 16 + lr]);

    const size_t chunk = (size_t)(blockIdx.x * 4 + c16) * 5 + blockIdx.y;
    *(bf16x8*)((short*)w2f + chunk * 512 + lane * 8) = v;
}

// ---------------- K1': FUSED h -> t -> tf (h,t never touch HBM) ------------
// Block = 16 rows (one r16 chunk group), 512 threads, grid 256. (R14-verified)
__global__ __launch_bounds__(512) void dec_fused_kernel(
    const float* __restrict__ digits,   // [R,10]
    const float* __restrict__ styles,   // [R,50]
    const float* __restrict__ Wh,       // [60,512]
    const float* __restrict__ bh,       // [512]
    const float* __restrict__ W1,       // [512,160]
    const float* __restrict__ b1,       // [160]
    __hip_bfloat16* __restrict__ tf)    // [1280 chunks][512 shorts]
{
    __shared__ float cat_s[16][60];     // 3.75 KB
    __shared__ float h_s[16 * 512];     // 32 KB
    __shared__ float t_s[16][161];      // 10.1 KB (pad: conflict-free pack)

    const int tid = threadIdx.x;
    const int rowBase = blockIdx.x * 16;

    // ---- A: stage concat rows ----
    for (int i = tid; i < 16 * 60; i += 512) {
        const int r = i / 60, k = i % 60;
        const int row = rowBase + r;
        cat_s[r][k] = (k < 10) ? digits[row * 10 + k]
                               : styles[row * 50 + (k - 10)];
    }
    __syncthreads();

    // ---- B: h = relu(cat @ Wh + bh); thread = one column, 16 rows ----
    {
        float acc[16];
        const float bias = bh[tid];
#pragma unroll
        for (int r = 0; r < 16; ++r) acc[r] = bias;
        for (int k = 0; k < 60; ++k) {
            const float w = Wh[k * 512 + tid];
#pragma unroll
            for (int r = 0; r < 16; ++r) acc[r] = fmaf(cat_s[r][k], w, acc[r]);
        }
#pragma unroll
        for (int r = 0; r < 16; ++r)
            h_s[r * 512 + tid] = fmaxf(acc[r], 0.0f);
    }
    __syncthreads();

    // ---- C: t = selu(h @ W1 + b1); 320 threads = 160 cols x 2 row-halves --
    if (tid < 320) {
        const int rh = (tid >= 160) ? 1 : 0;
        const int col = tid - rh * 160;
        const int r0 = rh * 8;
        float acc[8];
        const float bias = b1[col];
#pragma unroll
        for (int r = 0; r < 8; ++r) acc[r] = bias;

#pragma unroll 4
        for (int k = 0; k < 512; k += 4) {
            const float w0 = W1[(size_t)(k + 0) * 160 + col];
            const float w1 = W1[(size_t)(k + 1) * 160 + col];
            const float w2 = W1[(size_t)(k + 2) * 160 + col];
            const float w3 = W1[(size_t)(k + 3) * 160 + col];
#pragma unroll
            for (int r = 0; r < 8; ++r) {
                const float4 hv = *(const float4*)&h_s[(r0 + r) * 512 + k];
                float a = acc[r];
                a = fmaf(hv.x, w0, a);
                a = fmaf(hv.y, w1, a);
                a = fmaf(hv.z, w2, a);
                a = fmaf(hv.w, w3, a);
                acc[r] = a;
            }
        }
#pragma unroll
        for (int r = 0; r < 8; ++r) {
            const float z = acc[r];
            const float s = (z > 0.0f) ? (SELU_SCALE * z)
                                       : (SELU_SCALE * SELU_ALPHA * expm1f(z));
            t_s[r0 + r][col] = s;
        }
    }
    __syncthreads();

    // ---- D: pack 5 chunks (kk=0..4), 64 lanes each ----
    if (tid < 320) {
        const int kk = tid >> 6;        // 0..4
        const int l = tid & 63;
        const int lr = l & 15, lh = l >> 4;
        bf16x8 v;
#pragma unroll
        for (int j = 0; j < 8; ++j)
            v[j] = f2bf(t_s[lr][kk * 32 + lh * 8 + j]);
        *(bf16x8*)((short*)tf + ((size_t)blockIdx.x * 5 + kk) * 512 + l * 8) = v;
    }
}

// ---------------- K3: LDS-operand MFMA GEMM + fused BCE, split barrier -----
// grid (192, 32) col-fast; block 256 = 4 waves stacked on rows; tile 128x64.
// R16 structure (LDS-shared w2s + per-wave ims + reg bT/bc) with the barrier
// SPLIT (T4 counted vmcnt): issue bT/bc (L2 reg loads), then w2s DMAs, then
// ims DMAs (newest 8). s_waitcnt vmcnt(8) retires w2s + reg loads while the
// 8 image DMAs stay IN FLIGHT across a raw s_barrier; the GEMM (LDS/reg only)
// covers their HBM latency; vmcnt(0) lands just before the epilogue ds_reads.
__global__ __launch_bounds__(256, 3) void out_loss_mfma_kernel(
    const __hip_bfloat16* __restrict__ tf,   // fragment-packed t
    const __hip_bfloat16* __restrict__ w2f,  // fragment-packed W2
    const float* __restrict__ b2,            // [12288]
    const float* __restrict__ images,        // [4096,12288]
    float* __restrict__ out)                 // [4096,192]
{
    __shared__ short w2s[20 * 512];          // 20 KB: block's w2 chunks
    __shared__ float ims[4][2048];           // 32 KB: per-wave 32x64 images

    const int tid = threadIdx.x;
    const int lane = tid & 63;
    const int wv = tid >> 6;
    const int rowBase = blockIdx.y * 128 + wv * 32;
    const int colBase = blockIdx.x * 64;
    const int lr = lane & 15;
    const int lh = lane >> 4;

    const short* wfb = (const short*)w2f;
    const short* tfb = (const short*)tf;
    const char* imb = (const char*)images;

    // ---- (1) bT + bc register loads (L2-hot; oldest in the vmem queue) ----
    const int r16base = rowBase >> 4;
    bf16x8 bT[5][2];
#pragma unroll
    for (int kk = 0; kk < 5; ++kk)
#pragma unroll
        for (int r = 0; r < 2; ++r)
            bT[kk][r] = *(const bf16x8*)(tfb
                + ((size_t)(r16base + r) * 5 + kk) * 512 + lane * 8);
    float4 bc[4];
#pragma unroll
    for (int c = 0; c < 4; ++c)
        bc[c] = *(const float4*)(b2 + colBase + c * 16 + lh * 4);

    // ---- (2) w2s DMAs: 20 chunks, 5 per wave, shared across block ----
    {
        const size_t chunkBase = (size_t)blockIdx.x * 20;
#pragma unroll
        for (int tch = 0; tch < 5; ++tch) {
            const int cw = wv + tch * 4;
            __builtin_amdgcn_global_load_lds(
                (const uint32_t*)(wfb + (chunkBase + cw) * 512 + lane * 8),
                (uint32_t*)&w2s[cw * 512], 16, 0, 0);
        }
    }
    // ---- (3) ims DMAs: per-wave private 32x64, the NEWEST 8 vmem ops ----
    {
        const int rsub = lane >> 4;
        const int m = lane & 15;
#pragma unroll
        for (int w = 0; w < 8; ++w) {
            const int r = w * 4 + rsub;
            const size_t gb = (size_t)(rowBase + r) * 49152 + (size_t)colBase * 4
                            + (size_t)((16 * m) ^ ((r & 15) << 4));
            __builtin_amdgcn_global_load_lds((const uint32_t*)(imb + gb),
                (uint32_t*)&ims[wv][w * 256], 16, 0, 0);
        }
    }

    // counted fence: retire w2s + bT + bc; leave the 8 image DMAs in flight.
    asm volatile("s_waitcnt vmcnt(8)" ::: "memory");
    __builtin_amdgcn_sched_barrier(0);
    __builtin_amdgcn_s_barrier();            // raw barrier (no vmcnt(0) drain)

    // ---- GEMM: aW from LDS, bT from regs; images still streaming in ----
    f32x4 acc[4][2] = {};   // [cw][rw]
#pragma unroll
    for (int kk = 0; kk < 5; ++kk) {
        bf16x8 aW[4];
#pragma unroll
        for (int c = 0; c < 4; ++c)
            aW[c] = *(const bf16x8*)&w2s[(c * 5 + kk) * 512 + lane * 8];
#pragma unroll
        for (int c = 0; c < 4; ++c)
#pragma unroll
            for (int r = 0; r < 2; ++r)
                acc[c][r] = __builtin_amdgcn_mfma_f32_16x16x32_bf16(
                    aW[c], bT[kk][r], acc[c][r], 0, 0, 0);
    }

    // images landed by now (w2s-wait + GEMM covered the HBM latency)
    asm volatile("s_waitcnt vmcnt(0)" ::: "memory");
    __builtin_amdgcn_sched_barrier(0);

    // ---- epilogue: softplus(z) - z*img, reduce over 64 cols ----
    const float* myq = ims[wv];
#pragma unroll
    for (int rw = 0; rw < 2; ++rw) {
        float mx = 0.f;   // Σ max(z,0)
        float pr = 1.f;   // Π (1+e^{-|z|})  (16 terms, fp32-safe)
        float zi = 0.f;   // Σ z*im
#pragma unroll
        for (int c = 0; c < 4; ++c) {
            const int fidx = (rw * 16 + lr) * 64 + ((lh * 4 + c * 16) ^ (lr << 2));
            const float4 im4 = *(const float4*)&myq[fidx];   // ds_read_b128
            const float imv[4] = {im4.x, im4.y, im4.z, im4.w};
            const float bcv[4] = {bc[c].x, bc[c].y, bc[c].z, bc[c].w};
#pragma unroll
            for (int j = 0; j < 4; ++j) {
                const float z = acc[c][rw][j] + bcv[j];
                mx += fmaxf(z, 0.0f);
                pr *= 1.0f + __expf(-fabsf(z));   // native v_exp_f32
                zi = fmaf(z, imv[j], zi);
            }
        }
        float part = mx + __logf(pr) - zi;        // native v_log_f32

        // reduce over the 4 lh groups (each holds 16 of the 64 w-cols)
        part += __shfl_xor(part, 16);
        part += __shfl_xor(part, 32);

        if (lane < 16)
            out[(size_t)(rowBase + rw * 16 + lane) * 192 + blockIdx.x] = part;
    }
}

extern "C" void kernel_launch(void* const* d_in, const int* in_sizes, int n_in,
                              void* d_out, int out_size, void* d_ws, size_t ws_size,
                              hipStream_t stream) {
    const float* digits = (const float*)d_in[0];  // [8,512,10]
    const float* styles = (const float*)d_in[1];  // [8,512,50]
    const float* images = (const float*)d_in[2];  // [8,512,3,64,64]
    const float* Wh     = (const float*)d_in[3];  // [60,512]
    const float* bh     = (const float*)d_in[4];  // [512]
    const float* W1     = (const float*)d_in[5];  // [512,160]
    const float* b1     = (const float*)d_in[6];  // [160]
    const float* W2     = (const float*)d_in[7];  // [160,12288]
    const float* b2     = (const float*)d_in[8];  // [12288]
    float* out = (float*)d_out;                   // [4096,192]

    // workspace (~5.3 MB): w2f bf16 [3840*512] | tf bf16 [1280*512]
    __hip_bfloat16* w2f = (__hip_bfloat16*)d_ws;
    __hip_bfloat16* tf  = w2f + (size_t)12288 * 160;

    dim3 gridP(192, 5);
    w2_pack_kernel<<<gridP, 256, 0, stream>>>(W2, w2f);

    dec_fused_kernel<<<256, 512, 0, stream>>>(digits, styles, Wh, bh, W1, b1, tf);

    dim3 grid3(192, 32);
    out_loss_mfma_kernel<<<grid3, 256, 0, stream>>>(tf, w2f, b2, images, out);
}

// Round 18
// 82.587 us; speedup vs baseline: 1.4780x; 1.0372x over previous
//
#include <hip/hip_runtime.h>
#include <hip/hip_bf16.h>
#include <math.h>

// Decoder: h = relu(cat @ W_h + b_h); t = selu(h @ W1 + b1);
// x = sigmoid(t @ W2 + b2); loss = sum_w(softplus(z) - z*img)   [== -(BCE log-lik)]
// R = S*B = 4096 rows; Hn=512, bott=160, P=12288 = 192 groups * 64 (w).

#define SELU_SCALE 1.0507009873554804934193349852946f
#define SELU_ALPHA 1.6732632423543772848170429916717f

typedef __attribute__((ext_vector_type(8))) short bf16x8;   // 8 bf16 (4 VGPRs)
typedef __attribute__((ext_vector_type(4))) float f32x4;    // MFMA accumulator

static __device__ __forceinline__ short f2bf(float x) {
    __hip_bfloat16 h = __float2bfloat16(x);
    short s;
    __builtin_memcpy(&s, &h, 2);
    return s;
}

// ---------------- P: merged producer (dec_fused ∥ w2_pack) -----------------
// grid 736 x 512 threads. Blocks 0..255: fused h->t->tf for 16 rows each
// (R14-verified). Blocks 256..735: TWO w2_pack 32x64 tiles each (256-thread
// halves; R10-verified pack). Independent workloads now run CONCURRENTLY
// instead of as two serialized dispatches. LDS is a union (max 46.9 KB).
__global__ __launch_bounds__(512) void producer_kernel(
    const float* __restrict__ digits,   // [R,10]
    const float* __restrict__ styles,   // [R,50]
    const float* __restrict__ Wh,       // [60,512]
    const float* __restrict__ bh,       // [512]
    const float* __restrict__ W1,       // [512,160]
    const float* __restrict__ b1,       // [160]
    const float* __restrict__ W2,       // [160,12288]
    __hip_bfloat16* __restrict__ w2f,   // [3840 chunks][512 shorts]
    __hip_bfloat16* __restrict__ tf)    // [1280 chunks][512 shorts]
{
    __shared__ __align__(16) char smem[46912];
    const int tid = threadIdx.x;

    if (blockIdx.x < 256) {
        // ================= dec_fused role =================
        float (*cat_s)[60] = (float(*)[60])smem;              // 3.75 KB
        float* h_s = (float*)(smem + 3840);                   // 32 KB
        float (*t_s)[161] = (float(*)[161])(smem + 3840 + 32768); // 10.1 KB
        const int rowBase = blockIdx.x * 16;

        // ---- A: stage concat rows ----
        for (int i = tid; i < 16 * 60; i += 512) {
            const int r = i / 60, k = i % 60;
            const int row = rowBase + r;
            cat_s[r][k] = (k < 10) ? digits[row * 10 + k]
                                   : styles[row * 50 + (k - 10)];
        }
        __syncthreads();

        // ---- B: h = relu(cat @ Wh + bh); thread = one column, 16 rows ----
        {
            float acc[16];
            const float bias = bh[tid];
#pragma unroll
            for (int r = 0; r < 16; ++r) acc[r] = bias;
            for (int k = 0; k < 60; ++k) {
                const float w = Wh[k * 512 + tid];
#pragma unroll
                for (int r = 0; r < 16; ++r) acc[r] = fmaf(cat_s[r][k], w, acc[r]);
            }
#pragma unroll
            for (int r = 0; r < 16; ++r)
                h_s[r * 512 + tid] = fmaxf(acc[r], 0.0f);
        }
        __syncthreads();

        // ---- C: t = selu(h @ W1 + b1); 320 threads ----
        if (tid < 320) {
            const int rh = (tid >= 160) ? 1 : 0;
            const int col = tid - rh * 160;
            const int r0 = rh * 8;
            float acc[8];
            const float bias = b1[col];
#pragma unroll
            for (int r = 0; r < 8; ++r) acc[r] = bias;

#pragma unroll 4
            for (int k = 0; k < 512; k += 4) {
                const float w0 = W1[(size_t)(k + 0) * 160 + col];
                const float w1 = W1[(size_t)(k + 1) * 160 + col];
                const float w2 = W1[(size_t)(k + 2) * 160 + col];
                const float w3 = W1[(size_t)(k + 3) * 160 + col];
#pragma unroll
                for (int r = 0; r < 8; ++r) {
                    const float4 hv = *(const float4*)&h_s[(r0 + r) * 512 + k];
                    float a = acc[r];
                    a = fmaf(hv.x, w0, a);
                    a = fmaf(hv.y, w1, a);
                    a = fmaf(hv.z, w2, a);
                    a = fmaf(hv.w, w3, a);
                    acc[r] = a;
                }
            }
#pragma unroll
            for (int r = 0; r < 8; ++r) {
                const float z = acc[r];
                const float s = (z > 0.0f) ? (SELU_SCALE * z)
                                           : (SELU_SCALE * SELU_ALPHA * expm1f(z));
                t_s[r0 + r][col] = s;
            }
        }
        __syncthreads();

        // ---- D: pack 5 chunks (kk=0..4), 64 lanes each ----
        if (tid < 320) {
            const int kk = tid >> 6;
            const int l = tid & 63;
            const int lr = l & 15, lh = l >> 4;
            bf16x8 v;
#pragma unroll
            for (int j = 0; j < 8; ++j)
                v[j] = f2bf(t_s[lr][kk * 32 + lh * 8 + j]);
            *(bf16x8*)((short*)tf + ((size_t)blockIdx.x * 5 + kk) * 512 + l * 8) = v;
        }
    } else {
        // ================= w2_pack role (2 tiles per block) =================
        float (*tile)[64] = (float(*)[64])(smem + (tid >> 8) * 8192);
        const int p = (blockIdx.x - 256) * 2 + (tid >> 8);   // 0..959
        const int t256 = tid & 255;
        const int bx = p / 5, by = p % 5;
        const int colBase = bx * 64;
        const int kBase = by * 32;

        for (int i = t256; i < 32 * 64; i += 256)
            tile[i >> 6][i & 63] =
                W2[(size_t)(kBase + (i >> 6)) * 12288 + colBase + (i & 63)];
        __syncthreads();

        const int c16 = t256 >> 6;       // 0..3
        const int lane = t256 & 63;
        const int lr = lane & 15, lh = lane >> 4;

        bf16x8 v;
#pragma unroll
        for (int j = 0; j < 8; ++j)
            v[j] = f2bf(tile[lh * 8 + j][c16 * 16 + lr]);

        const size_t chunk = (size_t)(bx * 4 + c16) * 5 + by;
        *(bf16x8*)((short*)w2f + chunk * 512 + lane * 8) = v;
    }
}

// ---------------- K3: LDS-operand MFMA GEMM + fused BCE, split barrier -----
// grid (192, 32) col-fast; block 256 = 4 waves stacked on rows; tile 128x64.
// R17 structure: LDS-shared w2s + per-wave ims DMA + reg bT/bc; counted
// vmcnt(8) + raw s_barrier keeps the 8 image DMAs in flight across the GEMM.
// NEW: epilogue drain split -- vmcnt(4) before rw=0 (rows 0-15 = oldest 4
// DMAs), vmcnt(0) before rw=1 -- overlapping rw=0 math with the last DMAs.
__global__ __launch_bounds__(256, 3) void out_loss_mfma_kernel(
    const __hip_bfloat16* __restrict__ tf,   // fragment-packed t
    const __hip_bfloat16* __restrict__ w2f,  // fragment-packed W2
    const float* __restrict__ b2,            // [12288]
    const float* __restrict__ images,        // [4096,12288]
    float* __restrict__ out)                 // [4096,192]
{
    __shared__ short w2s[20 * 512];          // 20 KB: block's w2 chunks
    __shared__ float ims[4][2048];           // 32 KB: per-wave 32x64 images

    const int tid = threadIdx.x;
    const int lane = tid & 63;
    const int wv = tid >> 6;
    const int rowBase = blockIdx.y * 128 + wv * 32;
    const int colBase = blockIdx.x * 64;
    const int lr = lane & 15;
    const int lh = lane >> 4;

    const short* wfb = (const short*)w2f;
    const short* tfb = (const short*)tf;
    const char* imb = (const char*)images;

    // ---- (1) bT + bc register loads (L2-hot; oldest in the vmem queue) ----
    const int r16base = rowBase >> 4;
    bf16x8 bT[5][2];
#pragma unroll
    for (int kk = 0; kk < 5; ++kk)
#pragma unroll
        for (int r = 0; r < 2; ++r)
            bT[kk][r] = *(const bf16x8*)(tfb
                + ((size_t)(r16base + r) * 5 + kk) * 512 + lane * 8);
    float4 bc[4];
#pragma unroll
    for (int c = 0; c < 4; ++c)
        bc[c] = *(const float4*)(b2 + colBase + c * 16 + lh * 4);

    // ---- (2) w2s DMAs: 20 chunks, 5 per wave, shared across block ----
    {
        const size_t chunkBase = (size_t)blockIdx.x * 20;
#pragma unroll
        for (int tch = 0; tch < 5; ++tch) {
            const int cw = wv + tch * 4;
            __builtin_amdgcn_global_load_lds(
                (const uint32_t*)(wfb + (chunkBase + cw) * 512 + lane * 8),
                (uint32_t*)&w2s[cw * 512], 16, 0, 0);
        }
    }
    // ---- (3) ims DMAs: per-wave private 32x64, the NEWEST 8 vmem ops ----
    {
        const int rsub = lane >> 4;
        const int m = lane & 15;
#pragma unroll
        for (int w = 0; w < 8; ++w) {
            const int r = w * 4 + rsub;
            const size_t gb = (size_t)(rowBase + r) * 49152 + (size_t)colBase * 4
                            + (size_t)((16 * m) ^ ((r & 15) << 4));
            __builtin_amdgcn_global_load_lds((const uint32_t*)(imb + gb),
                (uint32_t*)&ims[wv][w * 256], 16, 0, 0);
        }
    }

    // counted fence: retire w2s + bT + bc; leave the 8 image DMAs in flight.
    asm volatile("s_waitcnt vmcnt(8)" ::: "memory");
    __builtin_amdgcn_sched_barrier(0);
    __builtin_amdgcn_s_barrier();            // raw barrier (no vmcnt(0) drain)

    // ---- GEMM: aW from LDS, bT from regs; images still streaming in ----
    f32x4 acc[4][2] = {};   // [cw][rw]
#pragma unroll
    for (int kk = 0; kk < 5; ++kk) {
        bf16x8 aW[4];
#pragma unroll
        for (int c = 0; c < 4; ++c)
            aW[c] = *(const bf16x8*)&w2s[(c * 5 + kk) * 512 + lane * 8];
#pragma unroll
        for (int c = 0; c < 4; ++c)
#pragma unroll
            for (int r = 0; r < 2; ++r)
                acc[c][r] = __builtin_amdgcn_mfma_f32_16x16x32_bf16(
                    aW[c], bT[kk][r], acc[c][r], 0, 0, 0);
    }

    // ---- epilogue: softplus(z) - z*img; split drain per rw half ----
    const float* myq = ims[wv];
#pragma unroll
    for (int rw = 0; rw < 2; ++rw) {
        if (rw == 0) {
            // rows 0-15 are DMAs w=0..3 (oldest): retire just those
            asm volatile("s_waitcnt vmcnt(4)" ::: "memory");
        } else {
            asm volatile("s_waitcnt vmcnt(0)" ::: "memory");
        }
        __builtin_amdgcn_sched_barrier(0);

        float mx = 0.f;   // Σ max(z,0)
        float pr = 1.f;   // Π (1+e^{-|z|})  (16 terms, fp32-safe)
        float zi = 0.f;   // Σ z*im
#pragma unroll
        for (int c = 0; c < 4; ++c) {
            const int fidx = (rw * 16 + lr) * 64 + ((lh * 4 + c * 16) ^ (lr << 2));
            const float4 im4 = *(const float4*)&myq[fidx];   // ds_read_b128
            const float imv[4] = {im4.x, im4.y, im4.z, im4.w};
            const float bcv[4] = {bc[c].x, bc[c].y, bc[c].z, bc[c].w};
#pragma unroll
            for (int j = 0; j < 4; ++j) {
                const float z = acc[c][rw][j] + bcv[j];
                mx += fmaxf(z, 0.0f);
                pr *= 1.0f + __expf(-fabsf(z));   // native v_exp_f32
                zi = fmaf(z, imv[j], zi);
            }
        }
        float part = mx + __logf(pr) - zi;        // native v_log_f32

        // reduce over the 4 lh groups (each holds 16 of the 64 w-cols)
        part += __shfl_xor(part, 16);
        part += __shfl_xor(part, 32);

        if (lane < 16)
            out[(size_t)(rowBase + rw * 16 + lane) * 192 + blockIdx.x] = part;
    }
}

extern "C" void kernel_launch(void* const* d_in, const int* in_sizes, int n_in,
                              void* d_out, int out_size, void* d_ws, size_t ws_size,
                              hipStream_t stream) {
    const float* digits = (const float*)d_in[0];  // [8,512,10]
    const float* styles = (const float*)d_in[1];  // [8,512,50]
    const float* images = (const float*)d_in[2];  // [8,512,3,64,64]
    const float* Wh     = (const float*)d_in[3];  // [60,512]
    const float* bh     = (const float*)d_in[4];  // [512]
    const float* W1     = (const float*)d_in[5];  // [512,160]
    const float* b1     = (const float*)d_in[6];  // [160]
    const float* W2     = (const float*)d_in[7];  // [160,12288]
    const float* b2     = (const float*)d_in[8];  // [12288]
    float* out = (float*)d_out;                   // [4096,192]

    // workspace (~5.3 MB): w2f bf16 [3840*512] | tf bf16 [1280*512]
    __hip_bfloat16* w2f = (__hip_bfloat16*)d_ws;
    __hip_bfloat16* tf  = w2f + (size_t)12288 * 160;

    producer_kernel<<<736, 512, 0, stream>>>(digits, styles, Wh, bh, W1, b1,
                                             W2, w2f, tf);

    dim3 grid3(192, 32);
    out_loss_mfma_kernel<<<grid3, 256, 0, stream>>>(tf, w2f, b2, images, out);
}

// Round 19
// 80.435 us; speedup vs baseline: 1.5175x; 1.0268x over previous
//
#include <hip/hip_runtime.h>
#include <hip/hip_bf16.h>
#include <math.h>

// Decoder: h = relu(cat @ W_h + b_h); t = selu(h @ W1 + b1);
// x = sigmoid(t @ W2 + b2); loss = sum_w(softplus(z) - z*img)   [== -(BCE log-lik)]
// R = S*B = 4096 rows; Hn=512, bott=160, P=12288 = 192 groups * 64 (w).

#define SELU_SCALE 1.0507009873554804934193349852946f
#define SELU_ALPHA 1.6732632423543772848170429916717f

typedef __attribute__((ext_vector_type(8))) short bf16x8;   // 8 bf16 (4 VGPRs)
typedef __attribute__((ext_vector_type(4))) float f32x4;    // MFMA accumulator

static __device__ __forceinline__ short f2bf(float x) {
    __hip_bfloat16 h = __float2bfloat16(x);
    short s;
    __builtin_memcpy(&s, &h, 2);
    return s;
}

// ---------------- P: merged producer (dec_fused ∥ w2_pack) -----------------
// (R18-verified, unchanged)
__global__ __launch_bounds__(512) void producer_kernel(
    const float* __restrict__ digits,   // [R,10]
    const float* __restrict__ styles,   // [R,50]
    const float* __restrict__ Wh,       // [60,512]
    const float* __restrict__ bh,       // [512]
    const float* __restrict__ W1,       // [512,160]
    const float* __restrict__ b1,       // [160]
    const float* __restrict__ W2,       // [160,12288]
    __hip_bfloat16* __restrict__ w2f,   // [3840 chunks][512 shorts]
    __hip_bfloat16* __restrict__ tf)    // [1280 chunks][512 shorts]
{
    __shared__ __align__(16) char smem[46912];
    const int tid = threadIdx.x;

    if (blockIdx.x < 256) {
        float (*cat_s)[60] = (float(*)[60])smem;
        float* h_s = (float*)(smem + 3840);
        float (*t_s)[161] = (float(*)[161])(smem + 3840 + 32768);
        const int rowBase = blockIdx.x * 16;

        for (int i = tid; i < 16 * 60; i += 512) {
            const int r = i / 60, k = i % 60;
            const int row = rowBase + r;
            cat_s[r][k] = (k < 10) ? digits[row * 10 + k]
                                   : styles[row * 50 + (k - 10)];
        }
        __syncthreads();

        {
            float acc[16];
            const float bias = bh[tid];
#pragma unroll
            for (int r = 0; r < 16; ++r) acc[r] = bias;
            for (int k = 0; k < 60; ++k) {
                const float w = Wh[k * 512 + tid];
#pragma unroll
                for (int r = 0; r < 16; ++r) acc[r] = fmaf(cat_s[r][k], w, acc[r]);
            }
#pragma unroll
            for (int r = 0; r < 16; ++r)
                h_s[r * 512 + tid] = fmaxf(acc[r], 0.0f);
        }
        __syncthreads();

        if (tid < 320) {
            const int rh = (tid >= 160) ? 1 : 0;
            const int col = tid - rh * 160;
            const int r0 = rh * 8;
            float acc[8];
            const float bias = b1[col];
#pragma unroll
            for (int r = 0; r < 8; ++r) acc[r] = bias;

#pragma unroll 4
            for (int k = 0; k < 512; k += 4) {
                const float w0 = W1[(size_t)(k + 0) * 160 + col];
                const float w1 = W1[(size_t)(k + 1) * 160 + col];
                const float w2 = W1[(size_t)(k + 2) * 160 + col];
                const float w3 = W1[(size_t)(k + 3) * 160 + col];
#pragma unroll
                for (int r = 0; r < 8; ++r) {
                    const float4 hv = *(const float4*)&h_s[(r0 + r) * 512 + k];
                    float a = acc[r];
                    a = fmaf(hv.x, w0, a);
                    a = fmaf(hv.y, w1, a);
                    a = fmaf(hv.z, w2, a);
                    a = fmaf(hv.w, w3, a);
                    acc[r] = a;
                }
            }
#pragma unroll
            for (int r = 0; r < 8; ++r) {
                const float z = acc[r];
                const float s = (z > 0.0f) ? (SELU_SCALE * z)
                                           : (SELU_SCALE * SELU_ALPHA * expm1f(z));
                t_s[r0 + r][col] = s;
            }
        }
        __syncthreads();

        if (tid < 320) {
            const int kk = tid >> 6;
            const int l = tid & 63;
            const int lr = l & 15, lh = l >> 4;
            bf16x8 v;
#pragma unroll
            for (int j = 0; j < 8; ++j)
                v[j] = f2bf(t_s[lr][kk * 32 + lh * 8 + j]);
            *(bf16x8*)((short*)tf + ((size_t)blockIdx.x * 5 + kk) * 512 + l * 8) = v;
        }
    } else {
        float (*tile)[64] = (float(*)[64])(smem + (tid >> 8) * 8192);
        const int p = (blockIdx.x - 256) * 2 + (tid >> 8);   // 0..959
        const int t256 = tid & 255;
        const int bx = p / 5, by = p % 5;
        const int colBase = bx * 64;
        const int kBase = by * 32;

        for (int i = t256; i < 32 * 64; i += 256)
            tile[i >> 6][i & 63] =
                W2[(size_t)(kBase + (i >> 6)) * 12288 + colBase + (i & 63)];
        __syncthreads();

        const int c16 = t256 >> 6;
        const int lane = t256 & 63;
        const int lr = lane & 15, lh = lane >> 4;

        bf16x8 v;
#pragma unroll
        for (int j = 0; j < 8; ++j)
            v[j] = f2bf(tile[lh * 8 + j][c16 * 16 + lr]);

        const size_t chunk = (size_t)(bx * 4 + c16) * 5 + by;
        *(bf16x8*)((short*)w2f + chunk * 512 + lane * 8) = v;
    }
}

// ---------------- K3: persistent rolling-pipeline MFMA GEMM + BCE loss -----
// grid (192 colgroups, 16); block 256 = 4 waves; col group FIXED per block;
// block runs 4 row-tiles of 64 rows (wave = 16 rows/tile).
//  - w2s (20 KB) staged ONCE via DMA; GEMM reads it from LDS (R16-verified).
//  - ims: per-wave 2 x 4 KB slabs, DMA'd one tile ahead (R6 swizzle).
//  - bT: 2 register banks, loaded one tile ahead.
//  - ONE counted s_waitcnt vmcnt(9) per iteration (= next tile's 5 bT + 4
//    ims stay in flight; never 0 mid-loop). ONE barrier total (w2s).
//  - loop body has ZERO stores (parts held in regs; stored after the loop)
//    so vmcnt counts are exact.
// Each wave keeps ~9 KB continuously in flight -> sustained HBM stream
// instead of R10-R18's burst-then-silent convoy.
__global__ __launch_bounds__(256, 3) void out_loss_mfma_kernel(
    const __hip_bfloat16* __restrict__ tf,   // fragment-packed t
    const __hip_bfloat16* __restrict__ w2f,  // fragment-packed W2
    const float* __restrict__ b2,            // [12288]
    const float* __restrict__ images,        // [4096,12288]
    float* __restrict__ out)                 // [4096,192]
{
    __shared__ short w2s[20 * 512];          // 20 KB: block's w2 chunks
    __shared__ float ims[4][2][1024];        // 32 KB: per-wave 2 slabs 16x64

    const int tid = threadIdx.x;
    const int lane = tid & 63;
    const int wv = tid >> 6;
    const int colBlk = blockIdx.x;           // 0..191 (fixed per block)
    const int colBase = colBlk * 64;
    const int lr = lane & 15;
    const int lh = lane >> 4;

    const short* wfb = (const short*)w2f;
    const short* tfb = (const short*)tf;
    const char* imb = (const char*)images;

    const int rsub = lane >> 4;               // DMA: row within instr
    const int m16 = lane & 15;                // DMA: 16B chunk in 256B row

    // wave's row base for tile it: blockIdx.y*256 + it*64 + wv*16
    const int rowW = blockIdx.y * 256 + wv * 16;

#define ISSUE_IMS(it_, slot_)                                                  \
    {                                                                          \
        const int rb = rowW + (it_) * 64;                                      \
        _Pragma("unroll")                                                      \
        for (int w = 0; w < 4; ++w) {                                          \
            const int r = w * 4 + rsub;                                        \
            const size_t gb = (size_t)(rb + r) * 49152 + (size_t)colBase * 4   \
                            + (size_t)((16 * m16) ^ ((r & 15) << 4));          \
            __builtin_amdgcn_global_load_lds((const uint32_t*)(imb + gb),      \
                (uint32_t*)&ims[wv][slot_][w * 256], 16, 0, 0);                \
        }                                                                      \
    }

#define ISSUE_BT(it_, bank_)                                                   \
    {                                                                          \
        const int r16 = (rowW + (it_) * 64) >> 4;                              \
        _Pragma("unroll")                                                      \
        for (int kk = 0; kk < 5; ++kk)                                         \
            bT[bank_][kk] = *(const bf16x8*)(tfb                               \
                + ((size_t)r16 * 5 + kk) * 512 + lane * 8);                    \
    }

    bf16x8 bT[2][5];

    // ---- prologue: bc, bT0, w2s, ims0 | bT1, ims1 ----
    float4 bc[4];
#pragma unroll
    for (int c = 0; c < 4; ++c)
        bc[c] = *(const float4*)(b2 + colBase + c * 16 + lh * 4);
    ISSUE_BT(0, 0)
    {
        const size_t chunkBase = (size_t)colBlk * 20;
#pragma unroll
        for (int tch = 0; tch < 5; ++tch) {
            const int cw = wv + tch * 4;
            __builtin_amdgcn_global_load_lds(
                (const uint32_t*)(wfb + (chunkBase + cw) * 512 + lane * 8),
                (uint32_t*)&w2s[cw * 512], 16, 0, 0);
        }
    }
    ISSUE_IMS(0, 0)
    ISSUE_BT(1, 1)
    ISSUE_IMS(1, 1)

    // retire bc..ims0 (15 ops); leave bT1+ims1 (9) in flight
    asm volatile("s_waitcnt vmcnt(9)" ::: "memory");
    __builtin_amdgcn_sched_barrier(0);
    __builtin_amdgcn_s_barrier();            // w2s visible to all waves

    float parts[4];

#pragma unroll
    for (int it = 0; it < 4; ++it) {
        if (it >= 1) {
            if (it < 3) {
                asm volatile("s_waitcnt vmcnt(9)" ::: "memory");
            } else {
                asm volatile("s_waitcnt vmcnt(0)" ::: "memory");
            }
            __builtin_amdgcn_sched_barrier(0);
        }

        // ---- GEMM: aW from LDS w2s, bT from regs (bank it&1) ----
        f32x4 acc[4] = {};
#pragma unroll
        for (int kk = 0; kk < 5; ++kk) {
            bf16x8 aW[4];
#pragma unroll
            for (int c = 0; c < 4; ++c)
                aW[c] = *(const bf16x8*)&w2s[(c * 5 + kk) * 512 + lane * 8];
#pragma unroll
            for (int c = 0; c < 4; ++c)
                acc[c] = __builtin_amdgcn_mfma_f32_16x16x32_bf16(
                    aW[c], bT[it & 1][kk], acc[c], 0, 0, 0);
        }

        // ---- slab -> regs, then fence before slab reuse ----
        float4 img[4];
#pragma unroll
        for (int c = 0; c < 4; ++c) {
            const int fidx = lr * 64 + ((lh * 4 + c * 16) ^ (lr << 2));
            img[c] = *(const float4*)&ims[wv][it & 1][fidx];  // ds_read_b128
        }
        asm volatile("s_waitcnt lgkmcnt(0)" ::: "memory");
        __builtin_amdgcn_sched_barrier(0);

        // ---- prefetch tile it+2 into the bank/slab just freed ----
        if (it < 2) {
            ISSUE_BT(it + 2, it & 1)
            ISSUE_IMS(it + 2, it & 1)
        }

        // ---- epilogue math (no stores) ----
        float mx = 0.f;   // Σ max(z,0)
        float pr = 1.f;   // Π (1+e^{-|z|})  (16 terms, fp32-safe)
        float zi = 0.f;   // Σ z*im
#pragma unroll
        for (int c = 0; c < 4; ++c) {
            const float imv[4] = {img[c].x, img[c].y, img[c].z, img[c].w};
            const float bcv[4] = {bc[c].x, bc[c].y, bc[c].z, bc[c].w};
#pragma unroll
            for (int j = 0; j < 4; ++j) {
                const float z = acc[c][j] + bcv[j];
                mx += fmaxf(z, 0.0f);
                pr *= 1.0f + __expf(-fabsf(z));   // native v_exp_f32
                zi = fmaf(z, imv[j], zi);
            }
        }
        float part = mx + __logf(pr) - zi;        // native v_log_f32
        part += __shfl_xor(part, 16);
        part += __shfl_xor(part, 32);

        if (it == 0)      parts[0] = part;
        else if (it == 1) parts[1] = part;
        else if (it == 2) parts[2] = part;
        else              parts[3] = part;
    }

    // ---- stores (outside the counted-vmcnt loop) ----
    if (lane < 16) {
#pragma unroll
        for (int it = 0; it < 4; ++it)
            out[(size_t)(rowW + it * 64 + lane) * 192 + colBlk] = parts[it];
    }
#undef ISSUE_IMS
#undef ISSUE_BT
}

extern "C" void kernel_launch(void* const* d_in, const int* in_sizes, int n_in,
                              void* d_out, int out_size, void* d_ws, size_t ws_size,
                              hipStream_t stream) {
    const float* digits = (const float*)d_in[0];  // [8,512,10]
    const float* styles = (const float*)d_in[1];  // [8,512,50]
    const float* images = (const float*)d_in[2];  // [8,512,3,64,64]
    const float* Wh     = (const float*)d_in[3];  // [60,512]
    const float* bh     = (const float*)d_in[4];  // [512]
    const float* W1     = (const float*)d_in[5];  // [512,160]
    const float* b1     = (const float*)d_in[6];  // [160]
    const float* W2     = (const float*)d_in[7];  // [160,12288]
    const float* b2     = (const float*)d_in[8];  // [12288]
    float* out = (float*)d_out;                   // [4096,192]

    // workspace (~5.3 MB): w2f bf16 [3840*512] | tf bf16 [1280*512]
    __hip_bfloat16* w2f = (__hip_bfloat16*)d_ws;
    __hip_bfloat16* tf  = w2f + (size_t)12288 * 160;

    producer_kernel<<<736, 512, 0, stream>>>(digits, styles, Wh, bh, W1, b1,
                                             W2, w2f, tf);

    dim3 grid3(192, 16);
    out_loss_mfma_kernel<<<grid3, 256, 0, stream>>>(tf, w2f, b2, images, out);
}

// Round 20
// 79.057 us; speedup vs baseline: 1.5440x; 1.0174x over previous
//
#include <hip/hip_runtime.h>
#include <hip/hip_bf16.h>
#include <math.h>

// Decoder: h = relu(cat @ W_h + b_h); t = selu(h @ W1 + b1);
// x = sigmoid(t @ W2 + b2); loss = sum_w(softplus(z) - z*img)   [== -(BCE log-lik)]
// R = S*B = 4096 rows; Hn=512, bott=160, P=12288 = 192 groups * 64 (w).

#define SELU_SCALE 1.0507009873554804934193349852946f
#define SELU_ALPHA 1.6732632423543772848170429916717f

typedef __attribute__((ext_vector_type(8))) short bf16x8;   // 8 bf16 (4 VGPRs)
typedef __attribute__((ext_vector_type(4))) float f32x4;    // MFMA accumulator

static __device__ __forceinline__ short f2bf(float x) {
    __hip_bfloat16 h = __float2bfloat16(x);
    short s;
    __builtin_memcpy(&s, &h, 2);
    return s;
}

// ---------------- P: merged producer (dec_fused ∥ w2_pack) -----------------
// (R18-verified, unchanged)
__global__ __launch_bounds__(512) void producer_kernel(
    const float* __restrict__ digits,   // [R,10]
    const float* __restrict__ styles,   // [R,50]
    const float* __restrict__ Wh,       // [60,512]
    const float* __restrict__ bh,       // [512]
    const float* __restrict__ W1,       // [512,160]
    const float* __restrict__ b1,       // [160]
    const float* __restrict__ W2,       // [160,12288]
    __hip_bfloat16* __restrict__ w2f,   // [3840 chunks][512 shorts]
    __hip_bfloat16* __restrict__ tf)    // [1280 chunks][512 shorts]
{
    __shared__ __align__(16) char smem[46912];
    const int tid = threadIdx.x;

    if (blockIdx.x < 256) {
        float (*cat_s)[60] = (float(*)[60])smem;
        float* h_s = (float*)(smem + 3840);
        float (*t_s)[161] = (float(*)[161])(smem + 3840 + 32768);
        const int rowBase = blockIdx.x * 16;

        for (int i = tid; i < 16 * 60; i += 512) {
            const int r = i / 60, k = i % 60;
            const int row = rowBase + r;
            cat_s[r][k] = (k < 10) ? digits[row * 10 + k]
                                   : styles[row * 50 + (k - 10)];
        }
        __syncthreads();

        {
            float acc[16];
            const float bias = bh[tid];
#pragma unroll
            for (int r = 0; r < 16; ++r) acc[r] = bias;
            for (int k = 0; k < 60; ++k) {
                const float w = Wh[k * 512 + tid];
#pragma unroll
                for (int r = 0; r < 16; ++r) acc[r] = fmaf(cat_s[r][k], w, acc[r]);
            }
#pragma unroll
            for (int r = 0; r < 16; ++r)
                h_s[r * 512 + tid] = fmaxf(acc[r], 0.0f);
        }
        __syncthreads();

        if (tid < 320) {
            const int rh = (tid >= 160) ? 1 : 0;
            const int col = tid - rh * 160;
            const int r0 = rh * 8;
            float acc[8];
            const float bias = b1[col];
#pragma unroll
            for (int r = 0; r < 8; ++r) acc[r] = bias;

#pragma unroll 4
            for (int k = 0; k < 512; k += 4) {
                const float w0 = W1[(size_t)(k + 0) * 160 + col];
                const float w1 = W1[(size_t)(k + 1) * 160 + col];
                const float w2 = W1[(size_t)(k + 2) * 160 + col];
                const float w3 = W1[(size_t)(k + 3) * 160 + col];
#pragma unroll
                for (int r = 0; r < 8; ++r) {
                    const float4 hv = *(const float4*)&h_s[(r0 + r) * 512 + k];
                    float a = acc[r];
                    a = fmaf(hv.x, w0, a);
                    a = fmaf(hv.y, w1, a);
                    a = fmaf(hv.z, w2, a);
                    a = fmaf(hv.w, w3, a);
                    acc[r] = a;
                }
            }
#pragma unroll
            for (int r = 0; r < 8; ++r) {
                const float z = acc[r];
                const float s = (z > 0.0f) ? (SELU_SCALE * z)
                                           : (SELU_SCALE * SELU_ALPHA * expm1f(z));
                t_s[r0 + r][col] = s;
            }
        }
        __syncthreads();

        if (tid < 320) {
            const int kk = tid >> 6;
            const int l = tid & 63;
            const int lr = l & 15, lh = l >> 4;
            bf16x8 v;
#pragma unroll
            for (int j = 0; j < 8; ++j)
                v[j] = f2bf(t_s[lr][kk * 32 + lh * 8 + j]);
            *(bf16x8*)((short*)tf + ((size_t)blockIdx.x * 5 + kk) * 512 + l * 8) = v;
        }
    } else {
        float (*tile)[64] = (float(*)[64])(smem + (tid >> 8) * 8192);
        const int p = (blockIdx.x - 256) * 2 + (tid >> 8);   // 0..959
        const int t256 = tid & 255;
        const int bx = p / 5, by = p % 5;
        const int colBase = bx * 64;
        const int kBase = by * 32;

        for (int i = t256; i < 32 * 64; i += 256)
            tile[i >> 6][i & 63] =
                W2[(size_t)(kBase + (i >> 6)) * 12288 + colBase + (i & 63)];
        __syncthreads();

        const int c16 = t256 >> 6;
        const int lane = t256 & 63;
        const int lr = lane & 15, lh = lane >> 4;

        bf16x8 v;
#pragma unroll
        for (int j = 0; j < 8; ++j)
            v[j] = f2bf(tile[lh * 8 + j][c16 * 16 + lr]);

        const size_t chunk = (size_t)(bx * 4 + c16) * 5 + by;
        *(bf16x8*)((short*)w2f + chunk * 512 + lane * 8) = v;
    }
}

// ---------------- K3: persistent rolling-pipeline MFMA GEMM + BCE loss -----
// 1-D grid 1536 with XCD-aware decode: colBlk = (bid&7)*24 + (bid>>3)%24,
// rowGen = bid/192. All 8 row-generations of a colBlk share bid%8 -> same
// XCD -> its 20 KB w2f chunk set is HBM-fetched ~once (was 16x in R19).
// Block = 4 waves; col group FIXED; EIGHT row-tiles of 64 rows (512 rows).
//  - w2s (20 KB) staged ONCE via DMA; GEMM reads from LDS (R16-verified).
//  - ims: per-wave 2 x 4 KB slabs, DMA'd one tile ahead (R6 swizzle).
//  - bT: 2 register banks, loaded one tile ahead.
//  - ONE counted s_waitcnt vmcnt(9) per iteration (T4; never 0 mid-loop).
//  - loop body has ZERO stores (parts in regs; stored after the loop).
__global__ __launch_bounds__(256, 3) void out_loss_mfma_kernel(
    const __hip_bfloat16* __restrict__ tf,   // fragment-packed t
    const __hip_bfloat16* __restrict__ w2f,  // fragment-packed W2
    const float* __restrict__ b2,            // [12288]
    const float* __restrict__ images,        // [4096,12288]
    float* __restrict__ out)                 // [4096,192]
{
    __shared__ short w2s[20 * 512];          // 20 KB: block's w2 chunks
    __shared__ float ims[4][2][1024];        // 32 KB: per-wave 2 slabs 16x64

    const int tid = threadIdx.x;
    const int lane = tid & 63;
    const int wv = tid >> 6;
    const int bid = blockIdx.x;              // 0..1535
    const int colBlk = (bid & 7) * 24 + ((bid >> 3) % 24);   // 0..191
    const int rowGen = bid / 192;            // 0..7
    const int colBase = colBlk * 64;
    const int lr = lane & 15;
    const int lh = lane >> 4;

    const short* wfb = (const short*)w2f;
    const short* tfb = (const short*)tf;
    const char* imb = (const char*)images;

    const int rsub = lane >> 4;               // DMA: row within instr
    const int m16 = lane & 15;                // DMA: 16B chunk in 256B row

    // wave's row base for tile it: rowGen*512 + it*64 + wv*16
    const int rowW = rowGen * 512 + wv * 16;

#define ISSUE_IMS(it_, slot_)                                                  \
    {                                                                          \
        const int rb = rowW + (it_) * 64;                                      \
        _Pragma("unroll")                                                      \
        for (int w = 0; w < 4; ++w) {                                          \
            const int r = w * 4 + rsub;                                        \
            const size_t gb = (size_t)(rb + r) * 49152 + (size_t)colBase * 4   \
                            + (size_t)((16 * m16) ^ ((r & 15) << 4));          \
            __builtin_amdgcn_global_load_lds((const uint32_t*)(imb + gb),      \
                (uint32_t*)&ims[wv][slot_][w * 256], 16, 0, 0);                \
        }                                                                      \
    }

#define ISSUE_BT(it_, bank_)                                                   \
    {                                                                          \
        const int r16 = (rowW + (it_) * 64) >> 4;                              \
        _Pragma("unroll")                                                      \
        for (int kk = 0; kk < 5; ++kk)                                         \
            bT[bank_][kk] = *(const bf16x8*)(tfb                               \
                + ((size_t)r16 * 5 + kk) * 512 + lane * 8);                    \
    }

    bf16x8 bT[2][5];

    // ---- prologue: bc, bT0, w2s, ims0 | bT1, ims1 ----
    float4 bc[4];
#pragma unroll
    for (int c = 0; c < 4; ++c)
        bc[c] = *(const float4*)(b2 + colBase + c * 16 + lh * 4);
    ISSUE_BT(0, 0)
    {
        const size_t chunkBase = (size_t)colBlk * 20;
#pragma unroll
        for (int tch = 0; tch < 5; ++tch) {
            const int cw = wv + tch * 4;
            __builtin_amdgcn_global_load_lds(
                (const uint32_t*)(wfb + (chunkBase + cw) * 512 + lane * 8),
                (uint32_t*)&w2s[cw * 512], 16, 0, 0);
        }
    }
    ISSUE_IMS(0, 0)
    ISSUE_BT(1, 1)
    ISSUE_IMS(1, 1)

    // retire bc..ims0 (15 ops); leave bT1+ims1 (9) in flight
    asm volatile("s_waitcnt vmcnt(9)" ::: "memory");
    __builtin_amdgcn_sched_barrier(0);
    __builtin_amdgcn_s_barrier();            // w2s visible to all waves

    float parts[8];

#pragma unroll
    for (int it = 0; it < 8; ++it) {
        if (it >= 1) {
            if (it < 7) {
                asm volatile("s_waitcnt vmcnt(9)" ::: "memory");
            } else {
                asm volatile("s_waitcnt vmcnt(0)" ::: "memory");
            }
            __builtin_amdgcn_sched_barrier(0);
        }

        // ---- GEMM: aW from LDS w2s, bT from regs (bank it&1) ----
        f32x4 acc[4] = {};
#pragma unroll
        for (int kk = 0; kk < 5; ++kk) {
            bf16x8 aW[4];
#pragma unroll
            for (int c = 0; c < 4; ++c)
                aW[c] = *(const bf16x8*)&w2s[(c * 5 + kk) * 512 + lane * 8];
#pragma unroll
            for (int c = 0; c < 4; ++c)
                acc[c] = __builtin_amdgcn_mfma_f32_16x16x32_bf16(
                    aW[c], bT[it & 1][kk], acc[c], 0, 0, 0);
        }

        // ---- slab -> regs, then fence before slab reuse ----
        float4 img[4];
#pragma unroll
        for (int c = 0; c < 4; ++c) {
            const int fidx = lr * 64 + ((lh * 4 + c * 16) ^ (lr << 2));
            img[c] = *(const float4*)&ims[wv][it & 1][fidx];  // ds_read_b128
        }
        asm volatile("s_waitcnt lgkmcnt(0)" ::: "memory");
        __builtin_amdgcn_sched_barrier(0);

        // ---- prefetch tile it+2 into the bank/slab just freed ----
        if (it < 6) {
            ISSUE_BT(it + 2, it & 1)
            ISSUE_IMS(it + 2, it & 1)
        }

        // ---- epilogue math (no stores) ----
        float mx = 0.f;   // Σ max(z,0)
        float pr = 1.f;   // Π (1+e^{-|z|})  (16 terms, fp32-safe)
        float zi = 0.f;   // Σ z*im
#pragma unroll
        for (int c = 0; c < 4; ++c) {
            const float imv[4] = {img[c].x, img[c].y, img[c].z, img[c].w};
            const float bcv[4] = {bc[c].x, bc[c].y, bc[c].z, bc[c].w};
#pragma unroll
            for (int j = 0; j < 4; ++j) {
                const float z = acc[c][j] + bcv[j];
                mx += fmaxf(z, 0.0f);
                pr *= 1.0f + __expf(-fabsf(z));   // native v_exp_f32
                zi = fmaf(z, imv[j], zi);
            }
        }
        float part = mx + __logf(pr) - zi;        // native v_log_f32
        part += __shfl_xor(part, 16);
        part += __shfl_xor(part, 32);

        parts[it] = part;                         // it is compile-time const
    }

    // ---- stores (outside the counted-vmcnt loop) ----
    if (lane < 16) {
#pragma unroll
        for (int it = 0; it < 8; ++it)
            out[(size_t)(rowW + it * 64 + lane) * 192 + colBlk] = parts[it];
    }
#undef ISSUE_IMS
#undef ISSUE_BT
}

extern "C" void kernel_launch(void* const* d_in, const int* in_sizes, int n_in,
                              void* d_out, int out_size, void* d_ws, size_t ws_size,
                              hipStream_t stream) {
    const float* digits = (const float*)d_in[0];  // [8,512,10]
    const float* styles = (const float*)d_in[1];  // [8,512,50]
    const float* images = (const float*)d_in[2];  // [8,512,3,64,64]
    const float* Wh     = (const float*)d_in[3];  // [60,512]
    const float* bh     = (const float*)d_in[4];  // [512]
    const float* W1     = (const float*)d_in[5];  // [512,160]
    const float* b1     = (const float*)d_in[6];  // [160]
    const float* W2     = (const float*)d_in[7];  // [160,12288]
    const float* b2     = (const float*)d_in[8];  // [12288]
    float* out = (float*)d_out;                   // [4096,192]

    // workspace (~5.3 MB): w2f bf16 [3840*512] | tf bf16 [1280*512]
    __hip_bfloat16* w2f = (__hip_bfloat16*)d_ws;
    __hip_bfloat16* tf  = w2f + (size_t)12288 * 160;

    producer_kernel<<<736, 512, 0, stream>>>(digits, styles, Wh, bh, W1, b1,
                                             W2, w2f, tf);

    out_loss_mfma_kernel<<<1536, 256, 0, stream>>>(tf, w2f, b2, images, out);
}